// Round 5
// baseline (301.917 us; speedup 1.0000x reference)
//
#include <hip/hip_runtime.h>
#include <hip/hip_bf16.h>
#include <hip/hip_fp16.h>

namespace {

constexpr int L_  = 16;
constexpr int P_  = 1024;
constexpr int DV_ = 64;
constexpr int DP_ = 16;
constexpr int B_  = 128;

constexpr size_t PB   = (size_t)P_ * B_;          // 131072
constexpr size_t SLV  = (size_t)B_ * L_ * DV_;    // 131072
constexpr size_t LPBT = (size_t)L_ * PB;          // 2M

constexpr int KCH = 32;           // wsum k-chunks (split-K over p)
constexpr int PPC = P_ / KCH;     // 32 p per wsum block
constexpr int MCHD = 64;          // dotv m-chunk blocks (each 8 pt = 16 p)

typedef _Float16 f16;
typedef __attribute__((ext_vector_type(8)))  _Float16 f16x8;
typedef __attribute__((ext_vector_type(16))) float    f32x16;

constexpr size_t WF_UNITS = (size_t)L_ * P_ * 2 * 64;   // f16x8 units, 2.1M
constexpr size_t WT_UNITS = (size_t)L_ * 512 * 4 * 64;  // f16x8 units, 2.1M

__device__ __forceinline__ f16x8 mul_pk(const __half2 cwh, const f16x8 f) {
  union { f16x8 v; __half2 h2[4]; } fu, bu;
  fu.v = f;
#pragma unroll
  for (int i = 0; i < 4; ++i) bu.h2[i] = __hmul2(cwh, fu.h2[i]);
  return bu.v;
}

// jbuf[p][b] = sel[b][p] + (b >= n_src ? n_src : 0); also feat f32->f16 tables
__global__ __launch_bounds__(256) void k_prep(
    const int* __restrict__ sel, const int* __restrict__ nsrc_p,
    int* __restrict__ jbuf, const float* __restrict__ feat,
    f16* __restrict__ feat16, f16* __restrict__ feat16s)
{
  const int i = blockIdx.x * 256 + threadIdx.x;   // b*1024 + p
  const int b = i >> 10, p = i & (P_ - 1);
  const int ns = *nsrc_p;
  jbuf[p * B_ + b] = sel[i] + (b >= ns ? ns : 0);
  if (i < B_ * DP_) {
    const float f = feat[i];
    feat16[i]  = (f16)f;
    feat16s[i] = (f16)(0.0625f * f);
  }
}

// W f32 -> two f16 fragment-major layouts.
// Wf unit (l,p,mt,lane): v = mt*32+(lane&31), q8 = (lane>>5)*8  (contiguous src)
// Wt unit (l,pt,ks,lane): p = pt*2+((lane&31)>>4), q = lane&15, v = ks*16+(lane>>5)*8+jv
__global__ __launch_bounds__(256) void k_cvtW(
    const float* __restrict__ W, f16* __restrict__ wf, f16* __restrict__ wt)
{
  const size_t id = (size_t)blockIdx.x * 256 + threadIdx.x;
  if (id < WF_UNITS) {
    const int lane = id & 63;
    const int mt   = (id >> 6) & 1;
    const size_t lp = id >> 7;                       // l*1024+p
    const int v  = mt * 32 + (lane & 31);
    const int q8 = (lane >> 5) * 8;
    const float* src = W + (lp * 64 + v) * 16 + q8;
    const float4 a = *(const float4*)src;
    const float4 b = *(const float4*)(src + 4);
    union { f16x8 v8; __half2 h2[4]; } o;
    o.h2[0] = __float22half2_rn(float2{a.x, a.y});
    o.h2[1] = __float22half2_rn(float2{a.z, a.w});
    o.h2[2] = __float22half2_rn(float2{b.x, b.y});
    o.h2[3] = __float22half2_rn(float2{b.z, b.w});
    reinterpret_cast<f16x8*>(wf)[id] = o.v8;
  } else {
    const size_t id2 = id - WF_UNITS;
    if (id2 >= WT_UNITS) return;
    const int lane = id2 & 63;
    const int ks   = (id2 >> 6) & 3;
    const size_t lpt = id2 >> 8;                     // l*512+pt
    const int l  = (int)(lpt >> 9);
    const int pt = (int)(lpt & 511);
    const int col = lane & 31;
    const int p  = pt * 2 + (col >> 4);
    const int q  = col & 15;
    const int vb = ks * 16 + (lane >> 5) * 8;
    const float* src = W + (((size_t)l * P_ + p) * 64 + vb) * 16 + q;
    float s[8];
#pragma unroll
    for (int jv = 0; jv < 8; ++jv) s[jv] = src[(size_t)jv * 16];
    union { f16x8 v8; __half2 h2[4]; } o;
#pragma unroll
    for (int i = 0; i < 4; ++i)
      o.h2[i] = __float22half2_rn(float2{s[2 * i], s[2 * i + 1]});
    reinterpret_cast<f16x8*>(wt)[id2] = o.v8;
  }
}

// spart[l][kc][v*128+b] = sum_{p in chunk, q} W * c * feat
template<bool UNIFORM>
__global__ __launch_bounds__(256) void k_wsum(
    const f16* __restrict__ wf, const f16* __restrict__ feat16,
    const f16* __restrict__ feat16s, const int* __restrict__ jbuf,
    const float* __restrict__ cbuf, float* __restrict__ spart)
{
  const int l    = blockIdx.y;
  const int kc   = blockIdx.x;
  const int wave = threadIdx.x >> 6;
  const int lane = threadIdx.x & 63;
  const int col  = lane & 31;
  const int h    = lane >> 5;
  const int bcol = wave * 32 + col;

  f32x16 accA0, accA1, accB0, accB1;
#pragma unroll
  for (int r = 0; r < 16; ++r) {
    accA0[r] = 0.f; accA1[r] = 0.f; accB0[r] = 0.f; accB1[r] = 0.f;
  }

  const int p0 = kc * PPC;
  const f16x8* wfu = reinterpret_cast<const f16x8*>(wf);
#pragma unroll 4
  for (int ps = 0; ps < PPC; ++ps) {
    const int p = p0 + ps;
    const size_t lp = (size_t)l * P_ + p;
    const int jj = jbuf[p * B_ + bcol];

    f16x8 bfrag;
    if (UNIFORM) {
      bfrag = *reinterpret_cast<const f16x8*>(feat16s + jj * DP_ + h * 8);
    } else {
      const float cw = cbuf[(size_t)l * PB + (size_t)p * B_ + bcol];
      const __half2 cwh = __float2half2_rn(cw);
      const f16x8 fr = *reinterpret_cast<const f16x8*>(feat16 + jj * DP_ + h * 8);
      bfrag = mul_pk(cwh, fr);
    }

    const f16x8 a0 = wfu[(lp * 2 + 0) * 64 + lane];
    const f16x8 a1 = wfu[(lp * 2 + 1) * 64 + lane];
    if (ps & 1) {
      accB0 = __builtin_amdgcn_mfma_f32_32x32x16_f16(a0, bfrag, accB0, 0, 0, 0);
      accB1 = __builtin_amdgcn_mfma_f32_32x32x16_f16(a1, bfrag, accB1, 0, 0, 0);
    } else {
      accA0 = __builtin_amdgcn_mfma_f32_32x32x16_f16(a0, bfrag, accA0, 0, 0, 0);
      accA1 = __builtin_amdgcn_mfma_f32_32x32x16_f16(a1, bfrag, accA1, 0, 0, 0);
    }
  }

  float* op = spart + ((size_t)l * KCH + kc) * ((size_t)DV_ * B_);
#pragma unroll
  for (int r = 0; r < 16; ++r) {
    const int v0 = (r & 3) + 8 * (r >> 2) + 4 * h;
    op[(size_t)v0 * B_ + bcol]        = accA0[r] + accB0[r];
    op[(size_t)(v0 + 32) * B_ + bcol] = accA1[r] + accB1[r];
  }
}

// d[l][p][b] = sum_v vv*u  (+bprev);  via C[(p,q),b] = sum_v Wt*vv, fold feat
template<bool ADDB>
__global__ __launch_bounds__(256) void k_dotv(
    const f16* __restrict__ wt, const float* __restrict__ feat,
    const int* __restrict__ jbuf, const float* __restrict__ vv,
    const float* __restrict__ bprev, float* __restrict__ dout)
{
  const int l    = blockIdx.y;
  const int mc   = blockIdx.x;
  const int wave = threadIdx.x >> 6;
  const int lane = threadIdx.x & 63;
  const int col  = lane & 31;
  const int h    = lane >> 5;
  const int bcol = wave * 32 + col;

  f16x8 bf[4];
#pragma unroll
  for (int ks = 0; ks < 4; ++ks) {
    const float* vp = vv + ((size_t)bcol * L_ + l) * DV_ + ks * 16 + h * 8;
    const float4 v0 = *(const float4*)vp, v1 = *(const float4*)(vp + 4);
    union { f16x8 v8; __half2 h2[4]; } u;
    u.h2[0] = __float22half2_rn(float2{v0.x, v0.y});
    u.h2[1] = __float22half2_rn(float2{v0.z, v0.w});
    u.h2[2] = __float22half2_rn(float2{v1.x, v1.y});
    u.h2[3] = __float22half2_rn(float2{v1.z, v1.w});
    bf[ks] = u.v8;
  }

  const int ptbase = mc * 8;
  const f16x8* wtu = reinterpret_cast<const f16x8*>(wt);

#pragma unroll 2
  for (int mt = 0; mt < 8; ++mt) {
    const int pt = ptbase + mt;
    const size_t lpt = (size_t)l * 512 + pt;

    f32x16 acc;
#pragma unroll
    for (int r = 0; r < 16; ++r) acc[r] = 0.f;

#pragma unroll
    for (int ks = 0; ks < 4; ++ks) {
      const f16x8 af = wtu[(lpt * 4 + ks) * 64 + lane];
      acc = __builtin_amdgcn_mfma_f32_32x32x16_f16(af, bf[ks], acc, 0, 0, 0);
    }

    const int p0 = pt * 2;
    const int j0 = jbuf[p0 * B_ + bcol];
    const int j1 = jbuf[(p0 + 1) * B_ + bcol];
    float d0 = 0.f, d1 = 0.f;
#pragma unroll
    for (int r = 0; r < 8; ++r) {
      const int q_r = (r & 3) + 8 * (r >> 2) + 4 * h;
      d0 = fmaf(acc[r],     feat[j0 * DP_ + q_r], d0);
      d1 = fmaf(acc[r + 8], feat[j1 * DP_ + q_r], d1);
    }
    d0 += __shfl_xor(d0, 32);
    d1 += __shfl_xor(d1, 32);
    if (h == 0) {
      const size_t o0 = (size_t)l * PB + (size_t)p0 * B_ + bcol;
      const size_t o1 = o0 + B_;
      float w0 = d0, w1 = d1;
      if (ADDB) { w0 += bprev[o0]; w1 += bprev[o1]; }
      dout[o0] = w0;
      dout[o1] = w1;
    }
  }
}

// softmax over l for each (p,b); buffers [l][p][b]
__global__ __launch_bounds__(256) void k_softmax_l(
    const float* __restrict__ lin, float* __restrict__ lout)
{
  const int idx = blockIdx.x * 256 + threadIdx.x;  // p*128 + b
  const float* ip = lin + idx;
  float x[L_];
  float m = -1e30f;
#pragma unroll
  for (int l = 0; l < L_; ++l) { x[l] = ip[(size_t)l * PB]; m = fmaxf(m, x[l]); }
  float den = 0.f;
#pragma unroll
  for (int l = 0; l < L_; ++l) { x[l] = __expf(x[l] - m); den += x[l]; }
  const float r = 1.f / den;
  float* op = lout + idx;
#pragma unroll
  for (int l = 0; l < L_; ++l) op[(size_t)l * PB] = x[l] * r;
}

// reduce spart over KCH chunks, then squash.
// grid = L * (B/4) blocks; 256 thr = 4 waves; wave = one b, lane = v.
template<bool FINAL>
__global__ __launch_bounds__(256) void k_reduce(
    const float* __restrict__ spart, float* __restrict__ vout,
    float* __restrict__ norms)
{
  const int bid = blockIdx.x;                    // l*32 + bg
  const int l  = bid >> 5;
  const int b  = (bid & 31) * 4 + (threadIdx.x >> 6);
  const int v  = threadIdx.x & 63;

  const float* sp = spart + (size_t)l * KCH * 8192 + (size_t)v * 128 + b;
  float x = 0.f;
#pragma unroll
  for (int c = 0; c < KCH; ++c) x += sp[(size_t)c * 8192];

  float t2 = x * x;
#pragma unroll
  for (int m = 32; m >= 1; m >>= 1) t2 += __shfl_xor(t2, m, 64);
  const float scale = sqrtf(t2) / (1.f + t2);

  vout[((size_t)b * L_ + l) * DV_ + v] = x * scale;
  if (FINAL && v == 0) norms[(size_t)l * B_ + b] = t2 / (1.f + t2);
}

} // namespace

extern "C" void kernel_launch(void* const* d_in, const int* in_sizes, int n_in,
                              void* d_out, int out_size, void* d_ws, size_t ws_size,
                              hipStream_t stream)
{
  (void)in_sizes; (void)n_in; (void)out_size; (void)ws_size;
  const float* feat   = (const float*)d_in[0];
  const int*   sel    = (const int*)d_in[1];
  const float* W      = (const float*)d_in[2];
  const int*   nsrc_p = (const int*)d_in[3];

  float* caps  = (float*)d_out;                 // [B,L,DV]
  float* norms = caps + SLV;                    // [L,B]

  // ws carve-up (f32 units; all 16B-aligned)
  float* base  = (float*)d_ws;
  f16*   wf     = (f16*)base;                                  // 16.8M f16
  f16*   wt     = (f16*)(base + WF_UNITS * 4);                 // 16.8M f16
  float* spart  = base + WF_UNITS * 8;                         // 4.2M f32
  float* bb1    = spart + (size_t)L_ * KCH * 8192;             // 2M
  float* bufc   = bb1 + LPBT;                                  // 2M
  float* v1     = bufc + LPBT;
  float* v2     = v1 + SLV;
  int*   jbuf   = (int*)(v2 + SLV);                            // 131072
  f16*   feat16 = (f16*)(jbuf + PB);                           // 2048 f16
  f16*   feat16s = feat16 + B_ * DP_;

  const dim3 blk(256);
  const dim3 gW(KCH, L_);
  const dim3 gD(MCHD, L_);
  const dim3 gF(512);
  const dim3 gR(L_ * (B_ / 4));                 // 512, wave-per-b
  const dim3 gC((unsigned)((WF_UNITS + WT_UNITS) / 256));

  k_prep<<<gF, blk, 0, stream>>>(sel, nsrc_p, jbuf, feat, feat16, feat16s);
  k_cvtW<<<gC, blk, 0, stream>>>(W, wf, wt);

  // iter 1: uniform c -> s1 -> v1 ; b1 = <v1,u>
  k_wsum<true><<<gW, blk, 0, stream>>>(wf, feat16, feat16s, jbuf, nullptr, spart);
  k_reduce<false><<<gR, blk, 0, stream>>>(spart, v1, nullptr);
  k_dotv<false><<<gD, blk, 0, stream>>>(wt, feat, jbuf, v1, nullptr, bb1);

  // iter 2: c2 = softmax(b1) -> s2 -> v2 ; b2 = b1 + <v2,u>
  k_softmax_l<<<gF, blk, 0, stream>>>(bb1, bufc);
  k_wsum<false><<<gW, blk, 0, stream>>>(wf, feat16, feat16s, jbuf, bufc, spart);
  k_reduce<false><<<gR, blk, 0, stream>>>(spart, v2, nullptr);
  k_dotv<true><<<gD, blk, 0, stream>>>(wt, feat, jbuf, v2, bb1, bufc);

  // final: c3 = softmax(b2) -> s3 -> caps/norms
  k_softmax_l<<<gF, blk, 0, stream>>>(bufc, bufc);
  k_wsum<false><<<gW, blk, 0, stream>>>(wf, feat16, feat16s, jbuf, bufc, spart);
  k_reduce<true><<<gR, blk, 0, stream>>>(spart, caps, norms);
}

// Round 6
// 284.299 us; speedup vs baseline: 1.0620x; 1.0620x over previous
//
#include <hip/hip_runtime.h>
#include <hip/hip_fp16.h>

namespace {

constexpr int L_  = 16;
constexpr int P_  = 1024;
constexpr int DV_ = 64;
constexpr int DP_ = 16;
constexpr int B_  = 128;

constexpr size_t PB   = (size_t)P_ * B_;          // 131072
constexpr size_t SLV  = (size_t)B_ * L_ * DV_;    // 131072
constexpr size_t LPBT = (size_t)L_ * PB;          // 2M

constexpr int KCH = 64;           // wsum split-K chunks (and dotv chunks)
constexpr int PPC = P_ / KCH;     // 16 p per block

typedef _Float16 f16;
typedef __attribute__((ext_vector_type(8)))  _Float16 f16x8;
typedef __attribute__((ext_vector_type(16))) float    f32x16;

constexpr size_t WF_UNITS = (size_t)L_ * P_ * 2 * 64;   // f16x8 units (33.5 MB)

__device__ __forceinline__ f16x8 mul_pk(const __half2 cwh, const f16x8 f) {
  union { f16x8 v; __half2 h2[4]; } fu, bu;
  fu.v = f;
#pragma unroll
  for (int i = 0; i < 4; ++i) bu.h2[i] = __hmul2(cwh, fu.h2[i]);
  return bu.v;
}

// Build wf (f16 A-fragment-major W) and xq/xqs (gathered, f16 B-source).
// wf unit (l,p,mt,lane): v = mt*32+(lane&31), q8 = (lane>>5)*8  (contiguous src)
// xq[p][b][q] = feat[j(b,p)][q];  xqs = xq/16.
__global__ __launch_bounds__(256) void k_prepcvt(
    const float* __restrict__ W, const float* __restrict__ feat,
    const int* __restrict__ sel, const int* __restrict__ nsrc_p,
    f16* __restrict__ wf, f16* __restrict__ xq, f16* __restrict__ xqs)
{
  const size_t id = (size_t)blockIdx.x * 256 + threadIdx.x;
  if (id < WF_UNITS) {
    const int lane = id & 63;
    const int mt   = (id >> 6) & 1;
    const size_t lp = id >> 7;                       // l*1024+p
    const int v  = mt * 32 + (lane & 31);
    const int q8 = (lane >> 5) * 8;
    const float* src = W + (lp * 64 + v) * 16 + q8;
    const float4 a = *(const float4*)src;
    const float4 b = *(const float4*)(src + 4);
    union { f16x8 v8; __half2 h2[4]; } o;
    o.h2[0] = __float22half2_rn(float2{a.x, a.y});
    o.h2[1] = __float22half2_rn(float2{a.z, a.w});
    o.h2[2] = __float22half2_rn(float2{b.x, b.y});
    o.h2[3] = __float22half2_rn(float2{b.z, b.w});
    reinterpret_cast<f16x8*>(wf)[id] = o.v8;
  } else {
    const size_t id2 = id - WF_UNITS;               // p*128 + b
    if (id2 >= PB) return;
    const int p = (int)(id2 >> 7);
    const int b = (int)(id2 & 127);
    const int ns = *nsrc_p;
    const int j = sel[b * P_ + p] + (b >= ns ? ns : 0);
    const float4 f0 = *(const float4*)(feat + j * DP_);
    const float4 f1 = *(const float4*)(feat + j * DP_ + 4);
    union { f16x8 v8; __half2 h2[4]; } o, os;
    o.h2[0] = __float22half2_rn(float2{f0.x, f0.y});
    o.h2[1] = __float22half2_rn(float2{f0.z, f0.w});
    o.h2[2] = __float22half2_rn(float2{f1.x, f1.y});
    o.h2[3] = __float22half2_rn(float2{f1.z, f1.w});
    const __half2 sc = __float2half2_rn(0.0625f);
#pragma unroll
    for (int i = 0; i < 4; ++i) os.h2[i] = __hmul2(sc, o.h2[i]);
    reinterpret_cast<f16x8*>(xq)[id2 * 2]      = o.v8;   // q 0..7 / 8..15
    reinterpret_cast<f16x8*>(xqs)[id2 * 2]     = os.v8;
    // second half (q 8..15) packed in same unit write? No: unit is 8 f16.
    // store second unit:
    // (handled below)
  }
}

// second-half writer for xq/xqs cannot fit above cleanly; do full 16 in one
// thread instead:  (replaces the partial logic — see k_prepcvt2)
__global__ __launch_bounds__(256) void k_prepcvt2(
    const float* __restrict__ feat, const int* __restrict__ sel,
    const int* __restrict__ nsrc_p, f16* __restrict__ xq, f16* __restrict__ xqs)
{
  const size_t id2 = (size_t)blockIdx.x * 256 + threadIdx.x;  // p*128+b
  if (id2 >= PB) return;
  const int p = (int)(id2 >> 7);
  const int b = (int)(id2 & 127);
  const int ns = *nsrc_p;
  const int j = sel[b * P_ + p] + (b >= ns ? ns : 0);
  const float4 f0 = *(const float4*)(feat + j * DP_);
  const float4 f1 = *(const float4*)(feat + j * DP_ + 4);
  const float4 f2 = *(const float4*)(feat + j * DP_ + 8);
  const float4 f3 = *(const float4*)(feat + j * DP_ + 12);
  union { f16x8 v8; __half2 h2[4]; } u0, u1, s0, s1;
  u0.h2[0] = __float22half2_rn(float2{f0.x, f0.y});
  u0.h2[1] = __float22half2_rn(float2{f0.z, f0.w});
  u0.h2[2] = __float22half2_rn(float2{f1.x, f1.y});
  u0.h2[3] = __float22half2_rn(float2{f1.z, f1.w});
  u1.h2[0] = __float22half2_rn(float2{f2.x, f2.y});
  u1.h2[1] = __float22half2_rn(float2{f2.z, f2.w});
  u1.h2[2] = __float22half2_rn(float2{f3.x, f3.y});
  u1.h2[3] = __float22half2_rn(float2{f3.z, f3.w});
  const __half2 sc = __float2half2_rn(0.0625f);
#pragma unroll
  for (int i = 0; i < 4; ++i) { s0.h2[i] = __hmul2(sc, u0.h2[i]); s1.h2[i] = __hmul2(sc, u1.h2[i]); }
  f16x8* xqu  = reinterpret_cast<f16x8*>(xq);
  f16x8* xqsu = reinterpret_cast<f16x8*>(xqs);
  xqu[id2 * 2]      = u0.v8;
  xqu[id2 * 2 + 1]  = u1.v8;
  xqsu[id2 * 2]     = s0.v8;
  xqsu[id2 * 2 + 1] = s1.v8;
}

// spart[l][kc][v*128+b] = sum_{p in chunk, q} W * c * xq
// grid.x = KCH*L, l = id&15 (XCD-pinned), kc = id>>4.
template<bool UNIFORM>
__global__ __launch_bounds__(256) void k_wsum(
    const f16* __restrict__ wf, const f16* __restrict__ xq,
    const f16* __restrict__ xqs, const float* __restrict__ cbuf,
    float* __restrict__ spart)
{
  const int id   = blockIdx.x;
  const int l    = id & 15;
  const int kc   = id >> 4;
  const int wave = threadIdx.x >> 6;
  const int lane = threadIdx.x & 63;
  const int col  = lane & 31;
  const int h    = lane >> 5;
  const int bcol = wave * 32 + col;

  f32x16 accA0, accA1, accB0, accB1;
#pragma unroll
  for (int r = 0; r < 16; ++r) {
    accA0[r] = 0.f; accA1[r] = 0.f; accB0[r] = 0.f; accB1[r] = 0.f;
  }

  const int p0 = kc * PPC;
  const f16x8* wfu  = reinterpret_cast<const f16x8*>(wf);
  const f16x8* xqu  = reinterpret_cast<const f16x8*>(UNIFORM ? xqs : xq);
#pragma unroll 4
  for (int ps = 0; ps < PPC; ++ps) {
    const int p = p0 + ps;
    const size_t lp = (size_t)l * P_ + p;

    f16x8 bfrag = xqu[(size_t)(p * B_ + bcol) * 2 + h];
    if (!UNIFORM) {
      const float cw = cbuf[(size_t)l * PB + (size_t)p * B_ + bcol];
      bfrag = mul_pk(__float2half2_rn(cw), bfrag);
    }

    const f16x8 a0 = wfu[(lp * 2 + 0) * 64 + lane];
    const f16x8 a1 = wfu[(lp * 2 + 1) * 64 + lane];
    if (ps & 1) {
      accB0 = __builtin_amdgcn_mfma_f32_32x32x16_f16(a0, bfrag, accB0, 0, 0, 0);
      accB1 = __builtin_amdgcn_mfma_f32_32x32x16_f16(a1, bfrag, accB1, 0, 0, 0);
    } else {
      accA0 = __builtin_amdgcn_mfma_f32_32x32x16_f16(a0, bfrag, accA0, 0, 0, 0);
      accA1 = __builtin_amdgcn_mfma_f32_32x32x16_f16(a1, bfrag, accA1, 0, 0, 0);
    }
  }

  float* op = spart + ((size_t)l * KCH + kc) * ((size_t)DV_ * B_);
#pragma unroll
  for (int r = 0; r < 16; ++r) {
    const int v0 = (r & 3) + 8 * (r >> 2) + 4 * h;
    op[(size_t)v0 * B_ + bcol]        = accA0[r] + accB0[r];
    op[(size_t)(v0 + 32) * B_ + bcol] = accA1[r] + accB1[r];
  }
}

// sres[l][v][b] = sum_kc spart[l][kc][v*128+b]   (coalesced; l-pinned)
__global__ __launch_bounds__(256) void k_rsum(
    const float* __restrict__ spart, float* __restrict__ sres)
{
  const int bid = blockIdx.x;                 // 512 = 16 l * 32 r
  const int l = bid & 15;
  const int r = bid >> 4;
  const int vb = r * 256 + threadIdx.x;       // 0..8191
  const float* sp = spart + (size_t)l * KCH * 8192 + vb;
  float x = 0.f;
#pragma unroll
  for (int c = 0; c < KCH; ++c) x += sp[(size_t)c * 8192];
  sres[(size_t)l * 8192 + vb] = x;
}

// squash: wave per b, lane = v.  non-final -> vvbuf[l][v][b];
// final -> caps[b][l][v] + norms[l][b].
template<bool FINAL>
__global__ __launch_bounds__(256) void k_squash(
    const float* __restrict__ sres, float* __restrict__ vout,
    float* __restrict__ norms)
{
  const int bid = blockIdx.x;                 // 512 = 16 l * 32 bg
  const int l  = bid & 15;
  const int b  = (bid >> 4) * 4 + (threadIdx.x >> 6);
  const int v  = threadIdx.x & 63;

  const float x = sres[(size_t)l * 8192 + (size_t)v * 128 + b];
  float t2 = x * x;
#pragma unroll
  for (int m = 32; m >= 1; m >>= 1) t2 += __shfl_xor(t2, m, 64);
  const float scale = sqrtf(t2) / (1.f + t2);

  if (FINAL) {
    vout[((size_t)b * L_ + l) * DV_ + v] = x * scale;
    if (v == 0) norms[(size_t)l * B_ + b] = t2 / (1.f + t2);
  } else {
    vout[(size_t)l * 8192 + (size_t)v * 128 + b] = x * scale;
  }
}

// d[l][p][b] = sum_v vv[l][v][b] * u[b,l,p,v]  (+bprev when ADDB)
// per p: u[v,b] = MFMA(wf, xq) with zero C-in; then in-register v-dot.
template<bool ADDB>
__global__ __launch_bounds__(256) void k_dotv(
    const f16* __restrict__ wf, const f16* __restrict__ xq,
    const float* __restrict__ vvbuf, const float* __restrict__ bprev,
    float* __restrict__ dout)
{
  const int id   = blockIdx.x;
  const int l    = id & 15;
  const int kc   = id >> 4;
  const int wave = threadIdx.x >> 6;
  const int lane = threadIdx.x & 63;
  const int col  = lane & 31;
  const int h    = lane >> 5;
  const int bcol = wave * 32 + col;

  // vv registers: vr0[r] = vv[l][v0(r)][bcol], vr1[r] = vv[l][v0(r)+32][bcol]
  float vr0[16], vr1[16];
  const float* vvl = vvbuf + (size_t)l * 8192 + bcol;
#pragma unroll
  for (int r = 0; r < 16; ++r) {
    const int v0 = (r & 3) + 8 * (r >> 2) + 4 * h;
    vr0[r] = vvl[(size_t)v0 * 128];
    vr1[r] = vvl[(size_t)(v0 + 32) * 128];
  }

  f32x16 zz;
#pragma unroll
  for (int r = 0; r < 16; ++r) zz[r] = 0.f;

  const int p0 = kc * PPC;
  const f16x8* wfu = reinterpret_cast<const f16x8*>(wf);
  const f16x8* xqu = reinterpret_cast<const f16x8*>(xq);

#pragma unroll 2
  for (int ps = 0; ps < PPC; ++ps) {
    const int p = p0 + ps;
    const size_t lp = (size_t)l * P_ + p;

    const f16x8 bfrag = xqu[(size_t)(p * B_ + bcol) * 2 + h];
    const f16x8 a0 = wfu[(lp * 2 + 0) * 64 + lane];
    const f16x8 a1 = wfu[(lp * 2 + 1) * 64 + lane];
    const f32x16 u0 = __builtin_amdgcn_mfma_f32_32x32x16_f16(a0, bfrag, zz, 0, 0, 0);
    const f32x16 u1 = __builtin_amdgcn_mfma_f32_32x32x16_f16(a1, bfrag, zz, 0, 0, 0);

    float d = 0.f;
#pragma unroll
    for (int r = 0; r < 16; ++r) {
      d = fmaf(u0[r], vr0[r], d);
      d = fmaf(u1[r], vr1[r], d);
    }
    d += __shfl_xor(d, 32);
    if (h == 0) {
      const size_t o = (size_t)l * PB + (size_t)p * B_ + bcol;
      dout[o] = ADDB ? d + bprev[o] : d;
    }
  }
}

// softmax over l for each (p,b); buffers [l][p][b]
__global__ __launch_bounds__(256) void k_softmax_l(
    const float* __restrict__ lin, float* __restrict__ lout)
{
  const int idx = blockIdx.x * 256 + threadIdx.x;  // p*128 + b
  const float* ip = lin + idx;
  float x[L_];
  float m = -1e30f;
#pragma unroll
  for (int l = 0; l < L_; ++l) { x[l] = ip[(size_t)l * PB]; m = fmaxf(m, x[l]); }
  float den = 0.f;
#pragma unroll
  for (int l = 0; l < L_; ++l) { x[l] = __expf(x[l] - m); den += x[l]; }
  const float r = 1.f / den;
  float* op = lout + idx;
#pragma unroll
  for (int l = 0; l < L_; ++l) op[(size_t)l * PB] = x[l] * r;
}

} // namespace

extern "C" void kernel_launch(void* const* d_in, const int* in_sizes, int n_in,
                              void* d_out, int out_size, void* d_ws, size_t ws_size,
                              hipStream_t stream)
{
  (void)in_sizes; (void)n_in; (void)out_size; (void)ws_size;
  const float* feat   = (const float*)d_in[0];
  const int*   sel    = (const int*)d_in[1];
  const float* W      = (const float*)d_in[2];
  const int*   nsrc_p = (const int*)d_in[3];

  float* caps  = (float*)d_out;                 // [B,L,DV]
  float* norms = caps + SLV;                    // [L,B]

  // ws carve-up (f32 units; 16B-aligned)
  float* base   = (float*)d_ws;
  f16*   wf     = (f16*)base;                                  // 33.5 MB
  float* spart  = base + WF_UNITS * 4;                         // 33.5 MB
  float* sres   = spart + (size_t)L_ * KCH * 8192;             // 512 KB
  float* vvbuf  = sres + SLV;                                  // 512 KB
  float* bb1    = vvbuf + SLV;                                 // 8 MB
  float* bufc   = bb1 + LPBT;                                  // 8 MB
  f16*   xq     = (f16*)(bufc + LPBT);                         // 4 MB
  f16*   xqs    = xq + PB * DP_;                               // 4 MB

  const dim3 blk(256);
  const dim3 gWf((unsigned)(WF_UNITS / 256));    // 8192
  const dim3 gX((unsigned)(PB / 256));           // 512
  const dim3 gH(KCH * L_);                       // 1024, l = id&15
  const dim3 gR(512);                            // rsum / squash / softmax
  // (k_prepcvt's xq tail is unused; xq is built by k_prepcvt2)

  k_prepcvt <<<gWf, blk, 0, stream>>>(W, feat, sel, nsrc_p, wf, xq, xqs);
  k_prepcvt2<<<gX,  blk, 0, stream>>>(feat, sel, nsrc_p, xq, xqs);

  // iter 1: uniform c -> s1 -> v1 ; b1 = <v1,u>
  k_wsum<true ><<<gH, blk, 0, stream>>>(wf, xq, xqs, nullptr, spart);
  k_rsum       <<<gR, blk, 0, stream>>>(spart, sres);
  k_squash<false><<<gR, blk, 0, stream>>>(sres, vvbuf, nullptr);
  k_dotv<false><<<gH, blk, 0, stream>>>(wf, xq, vvbuf, nullptr, bb1);

  // iter 2: c2 = softmax(b1) -> s2 -> v2 ; b2 = b1 + <v2,u>
  k_softmax_l  <<<gR, blk, 0, stream>>>(bb1, bufc);
  k_wsum<false><<<gH, blk, 0, stream>>>(wf, xq, xqs, bufc, spart);
  k_rsum       <<<gR, blk, 0, stream>>>(spart, sres);
  k_squash<false><<<gR, blk, 0, stream>>>(sres, vvbuf, nullptr);
  k_dotv<true ><<<gH, blk, 0, stream>>>(wf, xq, vvbuf, bb1, bufc);

  // final: c3 = softmax(b2) -> s3 -> caps/norms
  k_softmax_l  <<<gR, blk, 0, stream>>>(bufc, bufc);
  k_wsum<false><<<gH, blk, 0, stream>>>(wf, xq, xqs, bufc, spart);
  k_rsum       <<<gR, blk, 0, stream>>>(spart, sres);
  k_squash<true><<<gR, blk, 0, stream>>>(sres, caps, norms);
}

// Round 7
// 225.062 us; speedup vs baseline: 1.3415x; 1.2632x over previous
//
#include <hip/hip_runtime.h>
#include <hip/hip_fp16.h>

namespace {

constexpr int L_  = 16;
constexpr int P_  = 1024;
constexpr int DV_ = 64;
constexpr int DP_ = 16;
constexpr int B_  = 128;

constexpr size_t PB   = (size_t)P_ * B_;          // 131072
constexpr size_t SLV  = (size_t)B_ * L_ * DV_;    // 131072
constexpr size_t LPBT = (size_t)L_ * PB;          // 2M

constexpr int KCH = 64;           // split-K chunks (p-chunks per l)
constexpr int PPC = P_ / KCH;     // 16 p per heavy block

typedef _Float16 f16;
typedef __attribute__((ext_vector_type(4)))  _Float16 f16x4;
typedef __attribute__((ext_vector_type(8)))  _Float16 f16x8;
typedef __attribute__((ext_vector_type(16))) float    f32x16;

constexpr size_t WF_UNITS = (size_t)L_ * P_ * 2 * 64;   // f16x8 units (33.5 MB)

__device__ __forceinline__ f16x8 mul_pk(const __half2 cwh, const f16x8 f) {
  union { f16x8 v; __half2 h2[4]; } fu, bu;
  fu.v = f;
#pragma unroll
  for (int i = 0; i < 4; ++i) bu.h2[i] = __hmul2(cwh, fu.h2[i]);
  return bu.v;
}

// One launch: blocks [0,8192) build wf (l-pinned: l=bid&15 so wf slice lands
// in consumer XCD's L2); blocks [8192,8704) build gathered xq/xqs.
// wf unit (l,p,mt,lane): v = mt*32+(lane&31), q8 = (lane>>5)*8 (contiguous src)
// xq[p][b][q] = feat[j(b,p)][q]; xqs = xq/16.
__global__ __launch_bounds__(256) void k_prepcvt(
    const float* __restrict__ W, const float* __restrict__ feat,
    const int* __restrict__ sel, const int* __restrict__ nsrc_p,
    f16* __restrict__ wf, f16* __restrict__ xq, f16* __restrict__ xqs)
{
  const int bid = blockIdx.x, tid = threadIdx.x;
  if (bid < 8192) {
    const int l   = bid & 15;
    const int rem = (bid >> 4) * 256 + tid;        // [0,131072) within l
    const int lane = rem & 63;
    const int mt   = (rem >> 6) & 1;
    const int p    = rem >> 7;
    const int v  = mt * 32 + (lane & 31);
    const int q8 = (lane >> 5) * 8;
    const float* src = W + (((size_t)l * P_ + p) * 64 + v) * 16 + q8;
    const float4 a = *(const float4*)src;
    const float4 b = *(const float4*)(src + 4);
    union { f16x8 v8; __half2 h2[4]; } o;
    o.h2[0] = __float22half2_rn(float2{a.x, a.y});
    o.h2[1] = __float22half2_rn(float2{a.z, a.w});
    o.h2[2] = __float22half2_rn(float2{b.x, b.y});
    o.h2[3] = __float22half2_rn(float2{b.z, b.w});
    reinterpret_cast<f16x8*>(wf)[(size_t)l * 131072 + rem] = o.v8;
  } else {
    const int id2 = (bid - 8192) * 256 + tid;      // p*128 + b, exact cover
    const int p = id2 >> 7, b = id2 & 127;
    const int ns = *nsrc_p;
    const int j = sel[b * P_ + p] + (b >= ns ? ns : 0);
    const float4 f0 = *(const float4*)(feat + j * DP_);
    const float4 f1 = *(const float4*)(feat + j * DP_ + 4);
    const float4 f2 = *(const float4*)(feat + j * DP_ + 8);
    const float4 f3 = *(const float4*)(feat + j * DP_ + 12);
    union { f16x8 v8; __half2 h2[4]; } u0, u1, s0, s1;
    u0.h2[0] = __float22half2_rn(float2{f0.x, f0.y});
    u0.h2[1] = __float22half2_rn(float2{f0.z, f0.w});
    u0.h2[2] = __float22half2_rn(float2{f1.x, f1.y});
    u0.h2[3] = __float22half2_rn(float2{f1.z, f1.w});
    u1.h2[0] = __float22half2_rn(float2{f2.x, f2.y});
    u1.h2[1] = __float22half2_rn(float2{f2.z, f2.w});
    u1.h2[2] = __float22half2_rn(float2{f3.x, f3.y});
    u1.h2[3] = __float22half2_rn(float2{f3.z, f3.w});
    const __half2 sc = __float2half2_rn(0.0625f);
#pragma unroll
    for (int i = 0; i < 4; ++i) {
      s0.h2[i] = __hmul2(sc, u0.h2[i]);
      s1.h2[i] = __hmul2(sc, u1.h2[i]);
    }
    f16x8* xqu  = reinterpret_cast<f16x8*>(xq);
    f16x8* xqsu = reinterpret_cast<f16x8*>(xqs);
    xqu[(size_t)id2 * 2]      = u0.v8;
    xqu[(size_t)id2 * 2 + 1]  = u1.v8;
    xqsu[(size_t)id2 * 2]     = s0.v8;
    xqsu[(size_t)id2 * 2 + 1] = s1.v8;
  }
}

// spart[l][kc][b][v] (f16) = sum_{p in chunk, q} W * c * xq
// grid 1024: l = bid&15 (XCD-pinned), kc = bid>>4.
template<bool UNIFORM>
__global__ __launch_bounds__(256, 4) void k_wsum(
    const f16* __restrict__ wf, const f16* __restrict__ xq,
    const f16* __restrict__ xqs, const f16* __restrict__ cbuf,
    f16* __restrict__ spart)
{
  const int bid  = blockIdx.x;
  const int l    = bid & 15;
  const int kc   = bid >> 4;
  const int wave = threadIdx.x >> 6;
  const int lane = threadIdx.x & 63;
  const int col  = lane & 31;
  const int h    = lane >> 5;
  const int bcol = wave * 32 + col;

  f32x16 accA0, accA1, accB0, accB1;
#pragma unroll
  for (int r = 0; r < 16; ++r) {
    accA0[r] = 0.f; accA1[r] = 0.f; accB0[r] = 0.f; accB1[r] = 0.f;
  }

  const int p0 = kc * PPC;
  const f16x8* wfu = reinterpret_cast<const f16x8*>(wf);
  const f16x8* xqu = reinterpret_cast<const f16x8*>(UNIFORM ? xqs : xq);
#pragma unroll 4
  for (int ps = 0; ps < PPC; ++ps) {
    const int p = p0 + ps;
    const size_t lp = (size_t)l * P_ + p;

    f16x8 bfrag = xqu[(size_t)(p * B_ + bcol) * 2 + h];
    if (!UNIFORM) {
      const f16 cw = cbuf[(size_t)l * PB + (size_t)p * B_ + bcol];
      const __half hc = *reinterpret_cast<const __half*>(&cw);
      bfrag = mul_pk(__half2half2(hc), bfrag);
    }

    const f16x8 a0 = wfu[(lp * 2 + 0) * 64 + lane];
    const f16x8 a1 = wfu[(lp * 2 + 1) * 64 + lane];
    if (ps & 1) {
      accB0 = __builtin_amdgcn_mfma_f32_32x32x16_f16(a0, bfrag, accB0, 0, 0, 0);
      accB1 = __builtin_amdgcn_mfma_f32_32x32x16_f16(a1, bfrag, accB1, 0, 0, 0);
    } else {
      accA0 = __builtin_amdgcn_mfma_f32_32x32x16_f16(a0, bfrag, accA0, 0, 0, 0);
      accA1 = __builtin_amdgcn_mfma_f32_32x32x16_f16(a1, bfrag, accA1, 0, 0, 0);
    }
  }

  // b-major f16 epilogue: v0(r) = (r&3) + 8*(r>>2) + 4h -> 4-consecutive per group
  f16* op = spart + ((size_t)l * KCH + kc) * 8192 + (size_t)bcol * 64;
#pragma unroll
  for (int g = 0; g < 4; ++g) {
    f16x4 lo, hi;
#pragma unroll
    for (int j = 0; j < 4; ++j) {
      lo[j] = (f16)(accA0[g * 4 + j] + accB0[g * 4 + j]);
      hi[j] = (f16)(accA1[g * 4 + j] + accB1[g * 4 + j]);
    }
    *reinterpret_cast<f16x4*>(op + 8 * g + 4 * h)      = lo;
    *reinterpret_cast<f16x4*>(op + 32 + 8 * g + 4 * h) = hi;
  }
}

// sres[l][b][v] (f32) = sum_kc spart[l][kc][b][v]
// grid 128: l = bid&15, r = bid>>4 (8 slices); thread: 4 consecutive elems.
__global__ __launch_bounds__(256) void k_rsum(
    const f16* __restrict__ spart, float* __restrict__ sres)
{
  const int bid = blockIdx.x;
  const int l = bid & 15;
  const int r = bid >> 4;
  const int e = r * 1024 + threadIdx.x * 4;
  const f16* sp = spart + (size_t)l * KCH * 8192 + e;
  float a0 = 0.f, a1 = 0.f, a2 = 0.f, a3 = 0.f;
#pragma unroll
  for (int c = 0; c < KCH; ++c) {
    const f16x4 t = *reinterpret_cast<const f16x4*>(sp + (size_t)c * 8192);
    a0 += (float)t[0]; a1 += (float)t[1]; a2 += (float)t[2]; a3 += (float)t[3];
  }
  *reinterpret_cast<float4*>(sres + (size_t)l * 8192 + e) = float4{a0, a1, a2, a3};
}

// bb[l][p][b] (+)= sum_v squash(sres)[l][v][b] * u[b,l,p,v]
// squash fused: lane holds 32 v-vals of its b; sn via shfl_xor(32).
template<bool ADDB>
__global__ __launch_bounds__(256, 4) void k_dotv(
    const f16* __restrict__ wf, const f16* __restrict__ xq,
    const float* __restrict__ sres, float* __restrict__ bb)
{
  const int bid  = blockIdx.x;
  const int l    = bid & 15;
  const int kc   = bid >> 4;
  const int wave = threadIdx.x >> 6;
  const int lane = threadIdx.x & 63;
  const int col  = lane & 31;
  const int h    = lane >> 5;
  const int bcol = wave * 32 + col;

  float vr0[16], vr1[16];
  float sn = 0.f;
  const float* vp = sres + (size_t)l * 8192 + (size_t)bcol * 64;
#pragma unroll
  for (int g = 0; g < 4; ++g) {
    const float4 lo = *reinterpret_cast<const float4*>(vp + 8 * g + 4 * h);
    const float4 hi = *reinterpret_cast<const float4*>(vp + 32 + 8 * g + 4 * h);
    vr0[g * 4 + 0] = lo.x; vr0[g * 4 + 1] = lo.y;
    vr0[g * 4 + 2] = lo.z; vr0[g * 4 + 3] = lo.w;
    vr1[g * 4 + 0] = hi.x; vr1[g * 4 + 1] = hi.y;
    vr1[g * 4 + 2] = hi.z; vr1[g * 4 + 3] = hi.w;
    sn += lo.x * lo.x + lo.y * lo.y + lo.z * lo.z + lo.w * lo.w;
    sn += hi.x * hi.x + hi.y * hi.y + hi.z * hi.z + hi.w * hi.w;
  }
  sn += __shfl_xor(sn, 32);
  const float scale = sqrtf(sn) / (1.f + sn);
#pragma unroll
  for (int r = 0; r < 16; ++r) { vr0[r] *= scale; vr1[r] *= scale; }

  f32x16 zz;
#pragma unroll
  for (int r = 0; r < 16; ++r) zz[r] = 0.f;

  const int p0 = kc * PPC;
  const f16x8* wfu = reinterpret_cast<const f16x8*>(wf);
  const f16x8* xqu = reinterpret_cast<const f16x8*>(xq);

#pragma unroll 2
  for (int ps = 0; ps < PPC; ++ps) {
    const int p = p0 + ps;
    const size_t lp = (size_t)l * P_ + p;

    const f16x8 bfrag = xqu[(size_t)(p * B_ + bcol) * 2 + h];
    const f16x8 a0 = wfu[(lp * 2 + 0) * 64 + lane];
    const f16x8 a1 = wfu[(lp * 2 + 1) * 64 + lane];
    const f32x16 u0 = __builtin_amdgcn_mfma_f32_32x32x16_f16(a0, bfrag, zz, 0, 0, 0);
    const f32x16 u1 = __builtin_amdgcn_mfma_f32_32x32x16_f16(a1, bfrag, zz, 0, 0, 0);

    float d = 0.f;
#pragma unroll
    for (int r = 0; r < 16; ++r) {
      d = fmaf(u0[r], vr0[r], d);
      d = fmaf(u1[r], vr1[r], d);
    }
    d += __shfl_xor(d, 32);
    if (h == 0) {
      const size_t o = (size_t)l * PB + (size_t)p * B_ + bcol;
      bb[o] = ADDB ? d + bb[o] : d;
    }
  }
}

// c[l][p][b] (f16) = softmax over l of bb[l][p][b]
__global__ __launch_bounds__(256) void k_softmax(
    const float* __restrict__ lin, f16* __restrict__ cout)
{
  const int idx = blockIdx.x * 256 + threadIdx.x;  // p*128 + b
  const float* ip = lin + idx;
  float x[L_];
  float m = -1e30f;
#pragma unroll
  for (int l = 0; l < L_; ++l) { x[l] = ip[(size_t)l * PB]; m = fmaxf(m, x[l]); }
  float den = 0.f;
#pragma unroll
  for (int l = 0; l < L_; ++l) { x[l] = __expf(x[l] - m); den += x[l]; }
  const float r = 1.f / den;
  f16* op = cout + idx;
#pragma unroll
  for (int l = 0; l < L_; ++l) op[(size_t)l * PB] = (f16)(x[l] * r);
}

// final squash from sres[l][b][v]: caps[b][l][v] + norms[l][b]
__global__ __launch_bounds__(256) void k_squashF(
    const float* __restrict__ sres, float* __restrict__ caps,
    float* __restrict__ norms)
{
  const int bid = blockIdx.x;                 // 512 = 32 bg x 16 l
  const int l = bid & 15;
  const int b = (bid >> 4) * 4 + (threadIdx.x >> 6);
  const int v = threadIdx.x & 63;

  const float x = sres[(size_t)l * 8192 + (size_t)b * 64 + v];
  float t2 = x * x;
#pragma unroll
  for (int m = 32; m >= 1; m >>= 1) t2 += __shfl_xor(t2, m, 64);
  const float scale = sqrtf(t2) / (1.f + t2);

  caps[((size_t)b * L_ + l) * DV_ + v] = x * scale;
  if (v == 0) norms[(size_t)l * B_ + b] = t2 / (1.f + t2);
}

} // namespace

extern "C" void kernel_launch(void* const* d_in, const int* in_sizes, int n_in,
                              void* d_out, int out_size, void* d_ws, size_t ws_size,
                              hipStream_t stream)
{
  (void)in_sizes; (void)n_in; (void)out_size; (void)ws_size;
  const float* feat   = (const float*)d_in[0];
  const int*   sel    = (const int*)d_in[1];
  const float* W      = (const float*)d_in[2];
  const int*   nsrc_p = (const int*)d_in[3];

  float* caps  = (float*)d_out;                 // [B,L,DV]
  float* norms = caps + SLV;                    // [L,B]

  // ws carve-up (16B-aligned segments)
  char* base = (char*)d_ws;
  f16*   wf     = (f16*)base;                         base += WF_UNITS * 8 * 2;     // 33.5 MB
  f16*   spart  = (f16*)base;                         base += (size_t)L_ * KCH * 8192 * 2; // 16.8 MB
  float* sres   = (float*)base;                       base += (size_t)L_ * 8192 * 4; // 524 KB
  float* bb1    = (float*)base;                       base += LPBT * 4;              // 8.4 MB
  f16*   cbuf16 = (f16*)base;                         base += LPBT * 2;              // 4.2 MB
  f16*   xq     = (f16*)base;                         base += PB * DP_ * 2;          // 4.2 MB
  f16*   xqs    = (f16*)base;

  const dim3 blk(256);
  const dim3 gP(8704);          // wf (8192, l-pinned) + xq (512)
  const dim3 gH(KCH * L_);      // 1024 heavy blocks, l = bid&15
  const dim3 gRS(128);          // rsum
  const dim3 gS(512);           // softmax (p*128+b / 256)
  const dim3 gQ(512);           // final squash

  k_prepcvt<<<gP, blk, 0, stream>>>(W, feat, sel, nsrc_p, wf, xq, xqs);

  // iter 1: uniform c -> sres -> (squash in dotv) ; b1 = <v1,u>
  k_wsum<true ><<<gH, blk, 0, stream>>>(wf, xq, xqs, nullptr, spart);
  k_rsum       <<<gRS, blk, 0, stream>>>(spart, sres);
  k_dotv<false><<<gH, blk, 0, stream>>>(wf, xq, sres, bb1);

  // iter 2: c2 = softmax(b1) -> sres -> ; b2 = b1 + <v2,u> (in-place)
  k_softmax    <<<gS, blk, 0, stream>>>(bb1, cbuf16);
  k_wsum<false><<<gH, blk, 0, stream>>>(wf, xq, xqs, cbuf16, spart);
  k_rsum       <<<gRS, blk, 0, stream>>>(spart, sres);
  k_dotv<true ><<<gH, blk, 0, stream>>>(wf, xq, sres, bb1);

  // final: c3 = softmax(b2) -> sres -> caps/norms
  k_softmax    <<<gS, blk, 0, stream>>>(bb1, cbuf16);
  k_wsum<false><<<gH, blk, 0, stream>>>(wf, xq, xqs, cbuf16, spart);
  k_rsum       <<<gRS, blk, 0, stream>>>(spart, sres);
  k_squashF    <<<gQ, blk, 0, stream>>>(sres, caps, norms);
}

// Round 8
// 220.419 us; speedup vs baseline: 1.3697x; 1.0211x over previous
//
#include <hip/hip_runtime.h>
#include <hip/hip_fp16.h>

namespace {

constexpr int L_  = 16;
constexpr int P_  = 1024;
constexpr int DV_ = 64;
constexpr int DP_ = 16;
constexpr int B_  = 128;

constexpr size_t PB   = (size_t)P_ * B_;          // 131072
constexpr size_t SLV  = (size_t)B_ * L_ * DV_;    // 131072
constexpr size_t LPBT = (size_t)L_ * PB;          // 2M

constexpr int KCH = 64;           // split-K chunks (p-chunks per l)
constexpr int PPC = P_ / KCH;     // 16 p per heavy block

typedef _Float16 f16;
typedef __attribute__((ext_vector_type(4)))  _Float16 f16x4;
typedef __attribute__((ext_vector_type(8)))  _Float16 f16x8;
typedef __attribute__((ext_vector_type(16))) float    f32x16;

constexpr size_t WF_UNITS = (size_t)L_ * P_ * 2 * 64;   // f16x8 units (33.5 MB)

__device__ __forceinline__ f16x8 mul_pk(const __half2 cwh, const f16x8 f) {
  union { f16x8 v; __half2 h2[4]; } fu, bu;
  fu.v = f;
#pragma unroll
  for (int i = 0; i < 4; ++i) bu.h2[i] = __hmul2(cwh, fu.h2[i]);
  return bu.v;
}

// One launch: blocks [0,512) gather xq (latency-bound, start first);
// blocks [512, 512+8192) build wf l-pinned (l = wid&15).
// wf unit (l,p,mt,lane): v = mt*32+(lane&31), q8 = (lane>>5)*8 (contiguous src)
// xq[p][b][q] = feat[j(b,p)][q]  (f16)
__global__ __launch_bounds__(256) void k_prepcvt(
    const float* __restrict__ W, const float* __restrict__ feat,
    const int* __restrict__ sel, const int* __restrict__ nsrc_p,
    f16* __restrict__ wf, f16* __restrict__ xq)
{
  const int bid = blockIdx.x, tid = threadIdx.x;
  if (bid < 512) {
    const int id2 = bid * 256 + tid;               // p*128 + b
    const int p = id2 >> 7, b = id2 & 127;
    const int ns = *nsrc_p;
    const int j = sel[b * P_ + p] + (b >= ns ? ns : 0);
    const float4 f0 = *(const float4*)(feat + j * DP_);
    const float4 f1 = *(const float4*)(feat + j * DP_ + 4);
    const float4 f2 = *(const float4*)(feat + j * DP_ + 8);
    const float4 f3 = *(const float4*)(feat + j * DP_ + 12);
    union { f16x8 v8; __half2 h2[4]; } u0, u1;
    u0.h2[0] = __float22half2_rn(float2{f0.x, f0.y});
    u0.h2[1] = __float22half2_rn(float2{f0.z, f0.w});
    u0.h2[2] = __float22half2_rn(float2{f1.x, f1.y});
    u0.h2[3] = __float22half2_rn(float2{f1.z, f1.w});
    u1.h2[0] = __float22half2_rn(float2{f2.x, f2.y});
    u1.h2[1] = __float22half2_rn(float2{f2.z, f2.w});
    u1.h2[2] = __float22half2_rn(float2{f3.x, f3.y});
    u1.h2[3] = __float22half2_rn(float2{f3.z, f3.w});
    f16x8* xqu = reinterpret_cast<f16x8*>(xq);
    xqu[(size_t)id2 * 2]     = u0.v8;
    xqu[(size_t)id2 * 2 + 1] = u1.v8;
  } else {
    const int wid = bid - 512;
    const int l   = wid & 15;
    const int rem = (wid >> 4) * 256 + tid;        // [0,131072) within l
    const int lane = rem & 63;
    const int mt   = (rem >> 6) & 1;
    const int p    = rem >> 7;
    const int v  = mt * 32 + (lane & 31);
    const int q8 = (lane >> 5) * 8;
    const float* src = W + (((size_t)l * P_ + p) * 64 + v) * 16 + q8;
    const float4 a = *(const float4*)src;
    const float4 b = *(const float4*)(src + 4);
    union { f16x8 v8; __half2 h2[4]; } o;
    o.h2[0] = __float22half2_rn(float2{a.x, a.y});
    o.h2[1] = __float22half2_rn(float2{a.z, a.w});
    o.h2[2] = __float22half2_rn(float2{b.x, b.y});
    o.h2[3] = __float22half2_rn(float2{b.z, b.w});
    reinterpret_cast<f16x8*>(wf)[(size_t)l * 131072 + rem] = o.v8;
  }
}

// spart[l][kc][b][v] (f16) = sum_{p in chunk, q} W * c * xq   (c=1 if UNIFORM)
// grid 1024: l = bid&15 (XCD-pinned), kc = bid>>4.
template<bool UNIFORM>
__global__ __launch_bounds__(256, 4) void k_wsum(
    const f16* __restrict__ wf, const f16* __restrict__ xq,
    const f16* __restrict__ cbuf, f16* __restrict__ spart)
{
  const int bid  = blockIdx.x;
  const int l    = bid & 15;
  const int kc   = bid >> 4;
  const int wave = threadIdx.x >> 6;
  const int lane = threadIdx.x & 63;
  const int col  = lane & 31;
  const int h    = lane >> 5;
  const int bcol = wave * 32 + col;

  f32x16 accA0, accA1, accB0, accB1;
#pragma unroll
  for (int r = 0; r < 16; ++r) {
    accA0[r] = 0.f; accA1[r] = 0.f; accB0[r] = 0.f; accB1[r] = 0.f;
  }

  const int p0 = kc * PPC;
  const f16x8* wfu = reinterpret_cast<const f16x8*>(wf);
  const f16x8* xqu = reinterpret_cast<const f16x8*>(xq);
#pragma unroll 4
  for (int ps = 0; ps < PPC; ++ps) {
    const int p = p0 + ps;
    const size_t lp = (size_t)l * P_ + p;

    f16x8 bfrag = xqu[(size_t)(p * B_ + bcol) * 2 + h];
    if (!UNIFORM) {
      const f16 cw = cbuf[(size_t)l * PB + (size_t)p * B_ + bcol];
      const __half hc = *reinterpret_cast<const __half*>(&cw);
      bfrag = mul_pk(__half2half2(hc), bfrag);
    }

    const f16x8 a0 = wfu[(lp * 2 + 0) * 64 + lane];
    const f16x8 a1 = wfu[(lp * 2 + 1) * 64 + lane];
    if (ps & 1) {
      accB0 = __builtin_amdgcn_mfma_f32_32x32x16_f16(a0, bfrag, accB0, 0, 0, 0);
      accB1 = __builtin_amdgcn_mfma_f32_32x32x16_f16(a1, bfrag, accB1, 0, 0, 0);
    } else {
      accA0 = __builtin_amdgcn_mfma_f32_32x32x16_f16(a0, bfrag, accA0, 0, 0, 0);
      accA1 = __builtin_amdgcn_mfma_f32_32x32x16_f16(a1, bfrag, accA1, 0, 0, 0);
    }
  }

  // b-major f16 epilogue: v0(r) = (r&3) + 8*(r>>2) + 4h
  f16* op = spart + ((size_t)l * KCH + kc) * 8192 + (size_t)bcol * 64;
#pragma unroll
  for (int g = 0; g < 4; ++g) {
    f16x4 lo, hi;
#pragma unroll
    for (int j = 0; j < 4; ++j) {
      lo[j] = (f16)(accA0[g * 4 + j] + accB0[g * 4 + j]);
      hi[j] = (f16)(accA1[g * 4 + j] + accB1[g * 4 + j]);
    }
    *reinterpret_cast<f16x4*>(op + 8 * g + 4 * h)      = lo;
    *reinterpret_cast<f16x4*>(op + 32 + 8 * g + 4 * h) = hi;
  }
}

// sres[l][b][v] (f32) = sum_kc spart[l][kc][b][v]
__global__ __launch_bounds__(256) void k_rsum(
    const f16* __restrict__ spart, float* __restrict__ sres)
{
  const int bid = blockIdx.x;                 // 128 = 16 l * 8 r
  const int l = bid & 15;
  const int r = bid >> 4;
  const int e = r * 1024 + threadIdx.x * 4;
  const f16* sp = spart + (size_t)l * KCH * 8192 + e;
  float a0 = 0.f, a1 = 0.f, a2 = 0.f, a3 = 0.f;
#pragma unroll
  for (int c = 0; c < KCH; ++c) {
    const f16x4 t = *reinterpret_cast<const f16x4*>(sp + (size_t)c * 8192);
    a0 += (float)t[0]; a1 += (float)t[1]; a2 += (float)t[2]; a3 += (float)t[3];
  }
  *reinterpret_cast<float4*>(sres + (size_t)l * 8192 + e) = float4{a0, a1, a2, a3};
}

// bb[l][p][b] (f16) (+)= sum_v squash(SCALE*sres)[..] * u[b,l,p,v]
// squash fused: lane holds 32 v-vals of its b; sn via shfl_xor(32).
template<bool ADDB, bool SCALE>
__global__ __launch_bounds__(256, 4) void k_dotv(
    const f16* __restrict__ wf, const f16* __restrict__ xq,
    const float* __restrict__ sres, f16* __restrict__ bb)
{
  const int bid  = blockIdx.x;
  const int l    = bid & 15;
  const int kc   = bid >> 4;
  const int wave = threadIdx.x >> 6;
  const int lane = threadIdx.x & 63;
  const int col  = lane & 31;
  const int h    = lane >> 5;
  const int bcol = wave * 32 + col;

  float vr0[16], vr1[16];
  float sn = 0.f;
  const float* vp = sres + (size_t)l * 8192 + (size_t)bcol * 64;
#pragma unroll
  for (int g = 0; g < 4; ++g) {
    float4 lo = *reinterpret_cast<const float4*>(vp + 8 * g + 4 * h);
    float4 hi = *reinterpret_cast<const float4*>(vp + 32 + 8 * g + 4 * h);
    if (SCALE) {
      lo.x *= 0.0625f; lo.y *= 0.0625f; lo.z *= 0.0625f; lo.w *= 0.0625f;
      hi.x *= 0.0625f; hi.y *= 0.0625f; hi.z *= 0.0625f; hi.w *= 0.0625f;
    }
    vr0[g * 4 + 0] = lo.x; vr0[g * 4 + 1] = lo.y;
    vr0[g * 4 + 2] = lo.z; vr0[g * 4 + 3] = lo.w;
    vr1[g * 4 + 0] = hi.x; vr1[g * 4 + 1] = hi.y;
    vr1[g * 4 + 2] = hi.z; vr1[g * 4 + 3] = hi.w;
    sn += lo.x * lo.x + lo.y * lo.y + lo.z * lo.z + lo.w * lo.w;
    sn += hi.x * hi.x + hi.y * hi.y + hi.z * hi.z + hi.w * hi.w;
  }
  sn += __shfl_xor(sn, 32);
  const float scale = sqrtf(sn) / (1.f + sn);
#pragma unroll
  for (int r = 0; r < 16; ++r) { vr0[r] *= scale; vr1[r] *= scale; }

  f32x16 zz;
#pragma unroll
  for (int r = 0; r < 16; ++r) zz[r] = 0.f;

  const int p0 = kc * PPC;
  const f16x8* wfu = reinterpret_cast<const f16x8*>(wf);
  const f16x8* xqu = reinterpret_cast<const f16x8*>(xq);

#pragma unroll 2
  for (int ps = 0; ps < PPC; ++ps) {
    const int p = p0 + ps;
    const size_t lp = (size_t)l * P_ + p;

    const f16x8 bfrag = xqu[(size_t)(p * B_ + bcol) * 2 + h];
    const f16x8 a0 = wfu[(lp * 2 + 0) * 64 + lane];
    const f16x8 a1 = wfu[(lp * 2 + 1) * 64 + lane];
    const f32x16 u0 = __builtin_amdgcn_mfma_f32_32x32x16_f16(a0, bfrag, zz, 0, 0, 0);
    const f32x16 u1 = __builtin_amdgcn_mfma_f32_32x32x16_f16(a1, bfrag, zz, 0, 0, 0);

    float d = 0.f;
#pragma unroll
    for (int r = 0; r < 16; ++r) {
      d = fmaf(u0[r], vr0[r], d);
      d = fmaf(u1[r], vr1[r], d);
    }
    d += __shfl_xor(d, 32);
    if (h == 0) {
      const size_t o = (size_t)l * PB + (size_t)p * B_ + bcol;
      bb[o] = ADDB ? (f16)(d + (float)bb[o]) : (f16)d;
    }
  }
}

// c[l][p][b] (f16) = softmax over l of bb[l][p][b] (f16 in)
__global__ __launch_bounds__(256) void k_softmax(
    const f16* __restrict__ lin, f16* __restrict__ cout)
{
  const int idx = blockIdx.x * 256 + threadIdx.x;  // p*128 + b
  const f16* ip = lin + idx;
  float x[L_];
  float m = -1e30f;
#pragma unroll
  for (int l = 0; l < L_; ++l) { x[l] = (float)ip[(size_t)l * PB]; m = fmaxf(m, x[l]); }
  float den = 0.f;
#pragma unroll
  for (int l = 0; l < L_; ++l) { x[l] = __expf(x[l] - m); den += x[l]; }
  const float r = 1.f / den;
  f16* op = cout + idx;
#pragma unroll
  for (int l = 0; l < L_; ++l) op[(size_t)l * PB] = (f16)(x[l] * r);
}

// final: reduce spart over chunks AND squash -> caps/norms (no sres trip)
// grid 128 = 16 l * 8 r; thread: 4 consecutive v of b = r*16 + (t>>4).
__global__ __launch_bounds__(256) void k_rsumF(
    const f16* __restrict__ spart, float* __restrict__ caps,
    float* __restrict__ norms)
{
  const int bid = blockIdx.x;
  const int l = bid & 15;
  const int r = bid >> 4;
  const int t = threadIdx.x;
  const int e = r * 1024 + t * 4;            // [b][v] flat within l
  const int b = e >> 6;                      // r*16 + (t>>4)
  const int v4 = e & 63;

  const f16* sp = spart + (size_t)l * KCH * 8192 + e;
  float a0 = 0.f, a1 = 0.f, a2 = 0.f, a3 = 0.f;
#pragma unroll
  for (int c = 0; c < KCH; ++c) {
    const f16x4 q = *reinterpret_cast<const f16x4*>(sp + (size_t)c * 8192);
    a0 += (float)q[0]; a1 += (float)q[1]; a2 += (float)q[2]; a3 += (float)q[3];
  }

  float sn = a0 * a0 + a1 * a1 + a2 * a2 + a3 * a3;
#pragma unroll
  for (int m = 1; m <= 8; m <<= 1) sn += __shfl_xor(sn, m, 64);
  const float scale = sqrtf(sn) / (1.f + sn);

  float* cp = caps + ((size_t)b * L_ + l) * DV_ + v4;
  *reinterpret_cast<float4*>(cp) =
      float4{a0 * scale, a1 * scale, a2 * scale, a3 * scale};
  if ((t & 15) == 0) norms[(size_t)l * B_ + b] = sn / (1.f + sn);
}

} // namespace

extern "C" void kernel_launch(void* const* d_in, const int* in_sizes, int n_in,
                              void* d_out, int out_size, void* d_ws, size_t ws_size,
                              hipStream_t stream)
{
  (void)in_sizes; (void)n_in; (void)out_size; (void)ws_size;
  const float* feat   = (const float*)d_in[0];
  const int*   sel    = (const int*)d_in[1];
  const float* W      = (const float*)d_in[2];
  const int*   nsrc_p = (const int*)d_in[3];

  float* caps  = (float*)d_out;                 // [B,L,DV]
  float* norms = caps + SLV;                    // [L,B]

  // ws carve-up (16B-aligned segments)
  char* base = (char*)d_ws;
  f16*   wf     = (f16*)base;   base += WF_UNITS * 8 * 2;               // 33.5 MB
  f16*   spart  = (f16*)base;   base += (size_t)L_ * KCH * 8192 * 2;    // 16.8 MB
  float* sres   = (float*)base; base += (size_t)L_ * 8192 * 4;          // 524 KB
  f16*   bb1    = (f16*)base;   base += LPBT * 2;                       // 4.2 MB
  f16*   cbuf16 = (f16*)base;   base += LPBT * 2;                       // 4.2 MB
  f16*   xq     = (f16*)base;

  const dim3 blk(256);
  const dim3 gP(8704);          // xq (512, first) + wf (8192, l-pinned)
  const dim3 gH(KCH * L_);      // 1024 heavy blocks, l = bid&15
  const dim3 gRS(128);          // rsum / rsumF
  const dim3 gS(512);           // softmax

  k_prepcvt<<<gP, blk, 0, stream>>>(W, feat, sel, nsrc_p, wf, xq);

  // iter 1: uniform c (=1, 1/16 folded into dotv scale) -> b1 = <v1,u>
  k_wsum<true ><<<gH, blk, 0, stream>>>(wf, xq, nullptr, spart);
  k_rsum       <<<gRS, blk, 0, stream>>>(spart, sres);
  k_dotv<false, true><<<gH, blk, 0, stream>>>(wf, xq, sres, bb1);

  // iter 2: c2 = softmax(b1) -> s2 ; b2 = b1 + <v2,u> (in-place f16)
  k_softmax    <<<gS, blk, 0, stream>>>(bb1, cbuf16);
  k_wsum<false><<<gH, blk, 0, stream>>>(wf, xq, cbuf16, spart);
  k_rsum       <<<gRS, blk, 0, stream>>>(spart, sres);
  k_dotv<true, false><<<gH, blk, 0, stream>>>(wf, xq, sres, bb1);

  // final: c3 = softmax(b2) -> s3 -> caps/norms (fused reduce+squash)
  k_softmax    <<<gS, blk, 0, stream>>>(bb1, cbuf16);
  k_wsum<false><<<gH, blk, 0, stream>>>(wf, xq, cbuf16, spart);
  k_rsumF      <<<gRS, blk, 0, stream>>>(spart, caps, norms);
}